// Round 1
// baseline (191.089 us; speedup 1.0000x reference)
//
#include <hip/hip_runtime.h>

// Problem: B=16, T=1024, N=1024, D=256, WIN=64
// A = softmax(mask(QK^T/16)) restricted to window [prev_b, prev_b+64)
// outputs (flat, in order):
//   R          (B,T,2D)  = [A@V , Q]          : 16*1024*512  = 8388608 f32
//   alignments (B,N,T)   = A^T                : 16*1024*1024 = 16777216 f32
//   max_att    (B,T)     = argmax_n A (as f32): 16*1024      = 16384 f32
// Out-of-window softmax entries are exactly 0.0f (exp underflow), so we
// memset the alignments region and scatter only the 64 in-window values.

#define BB 16
#define TT 1024
#define NN 1024
#define DD 256
#define WIN 64

#define R_ELEMS   (16u*1024u*512u)        // 8388608
#define ALN_ELEMS (16u*1024u*1024u)       // 16777216

// One wave (64 lanes) handles 4 consecutive queries of one batch.
// lane = window column j. K row j is loaded once per d-chunk and reused
// across the 4 queries (4x L2-traffic amortization).
__global__ __launch_bounds__(64) void attn_kernel(
    const float* __restrict__ Q, const float* __restrict__ K,
    const float* __restrict__ V, const int* __restrict__ prev_in,
    float* __restrict__ out)
{
    float* Rout   = out;                       // (B,T,2D)
    float* aligns = out + R_ELEMS;             // (B,N,T)
    float* maxatt = out + R_ELEMS + ALN_ELEMS; // (B,T)

    const int lane  = threadIdx.x;        // 0..63 = window column j
    const int group = blockIdx.x;         // B*T/4 groups
    const int b  = group >> 8;            // 256 groups per batch
    const int t0 = (group & 255) * 4;
    const int prev = prev_in[b];

    const float* qb = Q + ((size_t)b * TT + t0) * DD;
    const float4* K4 = (const float4*)(K + ((size_t)b * NN + prev + lane) * DD);

    // ---- QK^T for 4 queries: lane j accumulates q_t . k_{prev+j} ----
    float acc[4] = {0.f, 0.f, 0.f, 0.f};
    for (int d4 = 0; d4 < DD / 4; ++d4) {
        float4 k = K4[d4];
        #pragma unroll
        for (int t = 0; t < 4; ++t) {
            float4 q = ((const float4*)(qb + t * DD))[d4];  // broadcast (same addr all lanes)
            acc[t] += q.x * k.x + q.y * k.y + q.z * k.z + q.w * k.w;
        }
    }

    // ---- softmax + argmax per query (all 64 scores live in the wave) ----
    float p[4];
    #pragma unroll
    for (int t = 0; t < 4; ++t) {
        float v = acc[t] * 0.0625f;  // 1/sqrt(256)

        float m = v;
        #pragma unroll
        for (int off = 32; off; off >>= 1)
            m = fmaxf(m, __shfl_xor(m, off));

        float e = expf(v - m);
        float s = e;
        #pragma unroll
        for (int off = 32; off; off >>= 1)
            s += __shfl_xor(s, off);

        p[t] = e / s;

        // argmax over logits == argmax over softmax (monotonic); first-index tiebreak
        float av = v; int ai = lane;
        #pragma unroll
        for (int off = 32; off; off >>= 1) {
            float ov = __shfl_xor(av, off);
            int   oi = __shfl_xor(ai, off);
            if (ov > av || (ov == av && oi < ai)) { av = ov; ai = oi; }
        }
        if (lane == 0)
            maxatt[(size_t)b * TT + t0 + t] = (float)(prev + ai);

        // alignments[b][prev+j][t] = p_j  (scatter, stride T between lanes)
        aligns[(size_t)b * NN * TT + (size_t)(prev + lane) * TT + (t0 + t)] = p[t];
    }

    // ---- PV: lane owns output dims [4*lane, 4*lane+4) ----
    const float4* V4 = (const float4*)(V + ((size_t)b * NN + prev) * DD);
    float4 o[4];
    #pragma unroll
    for (int t = 0; t < 4; ++t) o[t] = make_float4(0.f, 0.f, 0.f, 0.f);

    for (int j = 0; j < WIN; ++j) {
        float4 vv = V4[(size_t)j * (DD / 4) + lane];
        #pragma unroll
        for (int t = 0; t < 4; ++t) {
            float pj = __shfl(p[t], j);
            o[t].x += pj * vv.x;
            o[t].y += pj * vv.y;
            o[t].z += pj * vv.z;
            o[t].w += pj * vv.w;
        }
    }

    // ---- write R = [attn_out, Q] ----
    #pragma unroll
    for (int t = 0; t < 4; ++t) {
        float* Rrow = Rout + ((size_t)b * TT + t0 + t) * (2 * DD);
        ((float4*)Rrow)[lane] = o[t];
        ((float4*)(Rrow + DD))[lane] = ((const float4*)(qb + t * DD))[lane];
    }
}

extern "C" void kernel_launch(void* const* d_in, const int* in_sizes, int n_in,
                              void* d_out, int out_size, void* d_ws, size_t ws_size,
                              hipStream_t stream) {
    const float* Q = (const float*)d_in[0];
    const float* K = (const float*)d_in[1];
    const float* V = (const float*)d_in[2];
    const int* prev = (const int*)d_in[3];
    float* out = (float*)d_out;

    // Zero the alignments region (masked entries are exactly 0.0f).
    hipMemsetAsync(out + R_ELEMS, 0, (size_t)ALN_ELEMS * sizeof(float), stream);

    // One wave per 4 queries: B*T/4 = 4096 blocks of 64 threads.
    attn_kernel<<<BB * TT / 4, 64, 0, stream>>>(Q, K, V, prev, out);
}